// Round 9
// baseline (483.205 us; speedup 1.0000x reference)
//
#include <hip/hip_runtime.h>
#include <hip/hip_bf16.h>

// Problem constants
#define PP 64
#define BB 256
#define HH 512
#define MM (PP * BB)          // 16384 fused batch rows

// d_out layout: out (B,P,H) | hn (P,2,B,H) | cn (P,2,B,H)
#define HN_BASE (BB * PP * HH)                 // 8388608
#define CN_BASE (HN_BASE + PP * 2 * BB * HH)   // 25165824

// ---- workspace layout (bytes): FRAGMENT-ORDER bf16 tile images, BK=32 ----
// 8 KB tile = 512 slots of 16B, slot = rb*64 + lane (lane = qd*16 + lr):
//   A tiles [pb 0..127][kt32]: lane holds A[rb*16+lr][kt32*32 + qd*8 ..+8]
//   W tiles [hb 0..15][kt32]:  rb=g*2+half -> W row g*512+hb*32+half*16+lr
#define TILE8K 8192
#define WS_A0   0ull                          // h0[:,0]  image    16 MiB  (16 kt32)
#define WS_A1A  16777216ull                   // h_new0   image    16 MiB  (16 kt32)
#define WS_A1B  33554432ull                   // h0[:,1]  image    16 MiB  (16 kt32)
#define WS_W0   50331648ull                   // whh0  image   2 MiB (16 hb x 16 kt32)
#define WS_W1A  52428800ull                   // wih1  image   2 MiB
#define WS_W1B  54525952ull                   // whh1  image   2 MiB
#define WS_NEED 56623104ull

typedef __attribute__((ext_vector_type(8))) short bf16x8;
typedef __attribute__((ext_vector_type(4))) float floatx4;

__device__ __forceinline__ float sigf(float x) { return 1.0f / (1.0f + __expf(-x)); }
__device__ __forceinline__ float tanh_(float x) { return 2.0f / (1.0f + __expf(-2.0f * x)) - 1.0f; }

// float -> bf16 bits, round-nearest-even (finite inputs only)
__device__ __forceinline__ short f2bf(float f) {
  unsigned u = __float_as_uint(f);
  u = (u + 0x7FFFu + ((u >> 16) & 1u)) >> 16;
  return (short)u;
}

template <typename T>
__device__ __forceinline__ float tofl(T v);
template <> __device__ __forceinline__ float tofl<float>(float v) { return v; }
template <> __device__ __forceinline__ float tofl<__hip_bfloat16>(__hip_bfloat16 v) { return __bfloat162float(v); }

template <typename T>
__device__ __forceinline__ T fromfl(float v);
template <> __device__ __forceinline__ float fromfl<float>(float v) { return v; }
template <> __device__ __forceinline__ __hip_bfloat16 fromfl<__hip_bfloat16>(float v) { return __float2bfloat16(v); }

// load 8 consecutive elements as bf16x8 (16B-aligned for bf16, 32B for f32)
template <typename T>
__device__ __forceinline__ bf16x8 load8(const T* p);
template <> __device__ __forceinline__ bf16x8 load8<__hip_bfloat16>(const __hip_bfloat16* p) {
  return *(const bf16x8*)p;
}
template <> __device__ __forceinline__ bf16x8 load8<float>(const float* p) {
  float4 f0 = *(const float4*)p;
  float4 f1 = *((const float4*)p + 1);
  bf16x8 v;
  v[0] = f2bf(f0.x); v[1] = f2bf(f0.y); v[2] = f2bf(f0.z); v[3] = f2bf(f0.w);
  v[4] = f2bf(f1.x); v[5] = f2bf(f1.y); v[6] = f2bf(f1.z); v[7] = f2bf(f1.w);
  return v;
}

// fp32 vs bf16 buffer detection (see original kernel comment)
__device__ __forceinline__ bool detect_f32(const void* w_ih0) {
  const unsigned short* p = (const unsigned short*)w_ih0;
  int l = threadIdx.x & 63;
  unsigned short a = p[2 * l], b = p[2 * l + 1];
  int big = ((a & 0x7F80) >= 0x3F80) || ((b & 0x7F80) >= 0x3F80);
  return __any(big);
}

// async global -> LDS, 16 bytes per lane. LDS dest is wave-uniform + lane*16.
__device__ __forceinline__ void gload16(void* ldsp, const void* g) {
  __builtin_amdgcn_global_load_lds(
      (const __attribute__((address_space(1))) unsigned int*)g,
      (__attribute__((address_space(3))) unsigned int*)ldsp, 16, 0, 0);
}

// ============================================================================
// prep_panel: coalesced LDS-transpose of a [128 x 512] panel into 16 fragment
// tiles (8 KB each).  Reads 256B row-segments (coalesced), transposes through
// 16 KB LDS, dumps the image linearly (fully coalesced 16B/lane).
// Used for h0 slices AND (between layers) the h_new0 slice of d_out.
// ============================================================================
template <typename T>
__device__ __forceinline__ void prep_panel_body(const T* __restrict__ src, char* __restrict__ dst,
                                                char* lds) {
  const int tid = threadIdx.x;
  for (int cc = 0; cc < 8; ++cc) {          // 64-col chunk -> tiles kt=cc*2, cc*2+1
#pragma unroll
    for (int i = 0; i < 8; ++i) {
      int idx = i * 256 + tid;
      int row = idx >> 4;                    // 0..127 (16 lanes per row-segment)
      int c4  = idx & 15;                    // 4-elem group within the 64 cols
      int c   = c4 * 4;
      const T* p = src + (size_t)row * 512 + cc * 64 + c;
      short4 s;
      if constexpr (sizeof(T) == 4) {
        float4 f = *(const float4*)p;
        s.x = f2bf(f.x); s.y = f2bf(f.y); s.z = f2bf(f.z); s.w = f2bf(f.w);
      } else {
        s = *(const short4*)p;
      }
      int tile = c >> 5;                     // 0/1
      int qd   = (c & 31) >> 3;
      int e0   = c & 7;                      // 0 or 4
      int rb   = row >> 4, lr = row & 15;
      *(short4*)(lds + tile * 8192 + ((rb * 64 + qd * 16 + lr) * 16) + e0 * 2) = s;
    }
    __syncthreads();
#pragma unroll
    for (int i = 0; i < 4; ++i) {
      int idx = i * 256 + tid;               // 0..1023
      int kt  = cc * 2 + (idx >> 9);
      *(bf16x8*)(dst + (size_t)kt * TILE8K + (size_t)(idx & 511) * 16) =
          *(const bf16x8*)(lds + (size_t)idx * 16);
    }
    __syncthreads();
  }
}

// grid (128 pb, L), block 256.  tensor is (P,2,B,H); is_hn selects d_out+HN_BASE.
__global__ void __launch_bounds__(256)
prep_panel_k(const void* tensor, const void* det, void* ws,
             unsigned long long off0, unsigned long long off1, int is_hn) {
  const int pb = blockIdx.x, l = blockIdx.y;
  __shared__ __align__(16) char lds[16384];
  char* dst = (char*)ws + (l ? off1 : off0) + (size_t)pb * 16 * TILE8K;
  const size_t srcoff = (((size_t)(pb >> 1) * 2 + l) * 256 + (size_t)(pb & 1) * 128) * 512;
  if (detect_f32(det)) {
    const float* t = (const float*)tensor + (is_hn ? (size_t)HN_BASE : 0);
    prep_panel_body<float>(t + srcoff, dst, lds);
  } else {
    const __hip_bfloat16* t = (const __hip_bfloat16*)tensor + (is_hn ? (size_t)HN_BASE : 0);
    prep_panel_body<__hip_bfloat16>(t + srcoff, dst, lds);
  }
}

// ============================================================================
// W tiles from the three [2048,512] matrices. grid (48 = 3*16, 16 kt32), block 256.
// (only 12 MB total source — strided reads acceptable)
// ============================================================================
template <typename T>
__device__ __forceinline__ void prep_W_body(const T* __restrict__ w0, const T* __restrict__ w1a,
                                            const T* __restrict__ w1b, char* __restrict__ ws) {
  const int m = blockIdx.x >> 4, hb = blockIdx.x & 15, kt = blockIdx.y;
  const T* src = (m == 0) ? w0 : (m == 1 ? w1a : w1b);
  const size_t base = (m == 0) ? WS_W0 : (m == 1 ? WS_W1A : WS_W1B);
  char* dst = ws + base + ((size_t)(hb * 16 + kt)) * TILE8K;
  const int tid = threadIdx.x;
#pragma unroll
  for (int i = 0; i < 2; ++i) {
    int idx = i * 256 + tid;
    int ln  = idx & 63;
    int rb  = idx >> 6;               // rb = g*2 + half
    int g   = rb >> 1, half = rb & 1;
    int j   = g * 512 + hb * 32 + half * 16 + (ln & 15);   // row in [2048,512]
    int col = kt * 32 + (ln >> 4) * 8;
    *(bf16x8*)(dst + (size_t)idx * 16) = load8<T>(src + (size_t)j * 512 + col);
  }
}

__global__ void __launch_bounds__(256) prep_W_k(const void* w0, const void* w1a, const void* w1b,
                                                const void* det, void* ws) {
  if (detect_f32(det)) prep_W_body<float>((const float*)w0, (const float*)w1a, (const float*)w1b, (char*)ws);
  else prep_W_body<__hip_bfloat16>((const __hip_bfloat16*)w0, (const __hip_bfloat16*)w1a,
                                   (const __hip_bfloat16*)w1b, (char*)ws);
}

// ============================================================================
// Main layer kernel (R8 structure): BK=32 DMA double-buffer, plain
// __syncthreads per iteration.  1-D grid 2048 with bijective XCD-chunked
// swizzle so the 16 hb blocks sharing an A tile land on ONE XCD's L2.
// ============================================================================
template <typename T, int LAYER>
__device__ __forceinline__ void lstm_dma_body(
    const T* __restrict__ xin, const T* __restrict__ c0,
    const T* __restrict__ wih, const T* __restrict__ bih, const T* __restrict__ bhh,
    T* __restrict__ out, char* __restrict__ ws, char* lds)
{
  const int tid  = threadIdx.x;
  // XCD-chunked swizzle: 2048 = 8 XCDs x 256; same-nb blocks -> same XCD
  const int wg   = blockIdx.x;
  const int wgid = (wg & 7) * 256 + (wg >> 3);
  const int hb   = wgid & 15;    // h-block 0..15
  const int nb   = wgid >> 4;    // n-block 0..127 (== pb of A tiles)
  const int lane = tid & 63;
  const int wid  = tid >> 6;
  const int quad = lane >> 4;
  const int lrow = lane & 15;
  const int p0   = nb >> 1;

  floatx4 acc[4][4];             // [gate][mi]
#pragma unroll
  for (int g = 0; g < 4; ++g)
#pragma unroll
    for (int mi = 0; mi < 4; ++mi)
#pragma unroll
      for (int q = 0; q < 4; ++q) acc[g][mi][q] = 0.0f;

  const int a_rb0  = (wid >> 1) * 4;   // first A row-block for this wave
  const int w_half = wid & 1;

  constexpr int KITERS = (LAYER == 0) ? 16 : 32;   // K = 512 or 1024, BK=32

  auto stage = [&](int buf, int kt) {
    const char *at, *wt;
    if (LAYER == 0) {
      at = ws + WS_A0  + ((size_t)(nb * 16 + kt)) * TILE8K;
      wt = ws + WS_W0  + ((size_t)(hb * 16 + kt)) * TILE8K;
    } else if (kt < 16) {
      at = ws + WS_A1A + ((size_t)(nb * 16 + kt)) * TILE8K;
      wt = ws + WS_W1A + ((size_t)(hb * 16 + kt)) * TILE8K;
    } else {
      at = ws + WS_A1B + ((size_t)(nb * 16 + kt - 16)) * TILE8K;
      wt = ws + WS_W1B + ((size_t)(hb * 16 + kt - 16)) * TILE8K;
    }
    char* la = lds + buf * 16384;
    char* lw = la + TILE8K;
#pragma unroll
    for (int i = 0; i < 2; ++i) {
      int base = (i * 4 + wid) * 1024;       // wave-uniform LDS dest (verbatim copy)
      int off  = base + lane * 16;           // per-lane global source
      gload16(la + base, at + off);
      gload16(lw + base, wt + off);
    }
  };

  // prologue: fill buffer 0 (syncthreads' implicit vmcnt(0) drains the DMA)
  stage(0, 0);
  __syncthreads();

#pragma unroll
  for (int kt = 0; kt < KITERS; ++kt) {
    const int cur = kt & 1;
    if (kt + 1 < KITERS) stage(cur ^ 1, kt + 1);   // DMA in flight during MFMAs

    const char* la = lds + cur * 16384;
    const char* lw = la + TILE8K;
    bf16x8 aF[4], wF[4];
#pragma unroll
    for (int mi = 0; mi < 4; ++mi)
      aF[mi] = *(const bf16x8*)(la + ((a_rb0 + mi) * 1024) + lane * 16);
#pragma unroll
    for (int g = 0; g < 4; ++g)
      wF[g] = *(const bf16x8*)(lw + ((g * 2 + w_half) * 1024) + lane * 16);
#pragma unroll
    for (int g = 0; g < 4; ++g)
#pragma unroll
      for (int mi = 0; mi < 4; ++mi)
        acc[g][mi] = __builtin_amdgcn_mfma_f32_16x16x32_bf16(
            aF[mi], wF[g], acc[g][mi], 0, 0, 0);

    // barrier: (a) all waves done reading buf cur; (b) implicit vmcnt(0)
    // drain -> buf cur^1 DMA complete.
    __syncthreads();
  }

  // --- epilogue: biases + K=2 input GEMM (L0) + LSTM cell + stores ---
  const int hloc = hb * 32 + w_half * 16 + lrow;   // global h (C/D col = lane&15)
  float bias[4], wx0[4], wx1[4];
#pragma unroll
  for (int g = 0; g < 4; ++g) {
    int j = g * 512 + hloc;
    bias[g] = tofl<T>(bih[j]) + tofl<T>(bhh[j]);
    if (LAYER == 0) {
      wx0[g] = tofl<T>(wih[j * 2]);
      wx1[g] = tofl<T>(wih[j * 2 + 1]);
    }
  }
  const int crow0 = (p0 * 2 + LAYER) * 256;

#pragma unroll
  for (int mi = 0; mi < 4; ++mi) {
#pragma unroll
    for (int r = 0; r < 4; ++r) {
      // C/D layout: row(m=batch) = quad*4 + r, col(n=h) = lane&15
      int rr = (wid >> 1) * 64 + mi * 16 + quad * 4 + r;   // row within 128-row tile
      int b  = ((nb & 1) << 7) + rr;
      float gv0 = acc[0][mi][r] + bias[0];
      float gv1 = acc[1][mi][r] + bias[1];
      float gv2 = acc[2][mi][r] + bias[2];
      float gv3 = acc[3][mi][r] + bias[3];
      if (LAYER == 0) {
        float x0 = tofl<T>(xin[(b * 64 + p0) * 2]);
        float x1 = tofl<T>(xin[(b * 64 + p0) * 2 + 1]);
        gv0 += x0 * wx0[0] + x1 * wx1[0];
        gv1 += x0 * wx0[1] + x1 * wx1[1];
        gv2 += x0 * wx0[2] + x1 * wx1[2];
        gv3 += x0 * wx0[3] + x1 * wx1[3];
      }
      float ig = sigf(gv0), fg = sigf(gv1);
      float gg = tanh_(gv2), og = sigf(gv3);
      size_t ro = ((size_t)(crow0 + b)) * 512 + hloc;
      float co   = tofl<T>(c0[ro]);
      float cnew = fg * co + ig * gg;
      float hnew = og * tanh_(cnew);
      out[HN_BASE + ro] = fromfl<T>(hnew);
      out[CN_BASE + ro] = fromfl<T>(cnew);
      // (L0 handoff image is now built coalesced by prep_panel_k between layers)
      if (LAYER == 1)
        out[(size_t)(b * 64 + p0) * 512 + hloc] = fromfl<T>(hnew);
    }
  }
}

template <int LAYER>
__global__ void __launch_bounds__(256, 4)
lstm_dma(const void* xin, const void* c0, const void* wih,
         const void* bih, const void* bhh, const void* det,
         void* out, void* ws)
{
  __shared__ __align__(16) char lds[2 * 16384];   // dbuf x (A 8K + W 8K) = 32 KB
  if (detect_f32(det)) {
    lstm_dma_body<float, LAYER>((const float*)xin, (const float*)c0, (const float*)wih,
                                (const float*)bih, (const float*)bhh,
                                (float*)out, (char*)ws, lds);
  } else {
    lstm_dma_body<__hip_bfloat16, LAYER>((const __hip_bfloat16*)xin, (const __hip_bfloat16*)c0,
                                         (const __hip_bfloat16*)wih, (const __hip_bfloat16*)bih,
                                         (const __hip_bfloat16*)bhh,
                                         (__hip_bfloat16*)out, (char*)ws, lds);
  }
}

// ============================================================================
// Fallback (original verified kernel) — used if workspace is too small/absent.
// ============================================================================
template <typename T, int LAYER>
__device__ __forceinline__ void lstm_body(
    const T* __restrict__ xin, const T* __restrict__ h0, const T* __restrict__ c0,
    const T* __restrict__ wih, const T* __restrict__ whh,
    const T* __restrict__ bih, const T* __restrict__ bhh,
    T* out, __hip_bfloat16* ldsA, __hip_bfloat16* ldsW)
{
  const int tid  = threadIdx.x;
  const int nb   = blockIdx.x;
  const int hb   = blockIdx.y;
  const int lane = tid & 63;
  const int wid  = tid >> 6;
  const int quad = lane >> 4;
  const int lrow = lane & 15;
  const int p0   = nb >> 1;

  floatx4 acc[4][4];
#pragma unroll
  for (int g = 0; g < 4; ++g)
#pragma unroll
    for (int mi = 0; mi < 4; ++mi)
#pragma unroll
      for (int q = 0; q < 4; ++q) acc[g][mi][q] = 0.0f;

  int arow[4], wrow[4];
#pragma unroll
  for (int mi = 0; mi < 4; ++mi) arow[mi] = (wid >> 1) * 64 + mi * 16 + lrow;
#pragma unroll
  for (int g = 0; g < 4; ++g) wrow[g] = g * 32 + (wid & 1) * 16 + lrow;

  const int sr = tid >> 3;
  const int sc = tid & 7;
  const int KITERS = (LAYER == 0) ? 8 : 16;

  for (int kt = 0; kt < KITERS; ++kt) {
    bf16x8 ra[4], rw[4];
#pragma unroll
    for (int round = 0; round < 4; ++round) {
      int r = sr + round * 32;
      int b = ((nb & 1) << 7) + r;
      const T* srcA;
      if (LAYER == 0) {
        srcA = h0 + ((size_t)((p0 * 2) * 256 + b)) * 512 + kt * 64 + sc * 8;
      } else {
        if (kt < 8)
          srcA = out + HN_BASE + ((size_t)((p0 * 2) * 256 + b)) * 512 + kt * 64 + sc * 8;
        else
          srcA = h0 + ((size_t)((p0 * 2 + 1) * 256 + b)) * 512 + (kt - 8) * 64 + sc * 8;
      }
      ra[round] = load8<T>(srcA);

      int j = (r >> 5) * 512 + hb * 32 + (r & 31);
      const T* srcW;
      if (LAYER == 0) {
        srcW = whh + (size_t)j * 512 + kt * 64 + sc * 8;
      } else {
        if (kt < 8) srcW = wih + (size_t)j * 512 + kt * 64 + sc * 8;
        else        srcW = whh + (size_t)j * 512 + (kt - 8) * 64 + sc * 8;
      }
      rw[round] = load8<T>(srcW);
    }

    __syncthreads();
#pragma unroll
    for (int round = 0; round < 4; ++round) {
      int r = sr + round * 32;
      int p = sc ^ (r & 7);
      *(bf16x8*)((char*)ldsA + r * 128 + p * 16) = ra[round];
      *(bf16x8*)((char*)ldsW + r * 128 + p * 16) = rw[round];
    }
    __syncthreads();

#pragma unroll
    for (int ks = 0; ks < 2; ++ks) {
      bf16x8 aF[4], wF[4];
#pragma unroll
      for (int mi = 0; mi < 4; ++mi) {
        int ch = (ks * 4 + quad) ^ (arow[mi] & 7);
        aF[mi] = *(const bf16x8*)((const char*)ldsA + arow[mi] * 128 + ch * 16);
      }
#pragma unroll
      for (int g = 0; g < 4; ++g) {
        int ch = (ks * 4 + quad) ^ (wrow[g] & 7);
        wF[g] = *(const bf16x8*)((const char*)ldsW + wrow[g] * 128 + ch * 16);
      }
#pragma unroll
      for (int g = 0; g < 4; ++g)
#pragma unroll
        for (int mi = 0; mi < 4; ++mi)
          acc[g][mi] = __builtin_amdgcn_mfma_f32_16x16x32_bf16(
              aF[mi], wF[g], acc[g][mi], 0, 0, 0);
    }
  }

  const int hloc = hb * 32 + (wid & 1) * 16 + lrow;
  float bias[4], wx0[4], wx1[4];
#pragma unroll
  for (int g = 0; g < 4; ++g) {
    int j = g * 512 + hloc;
    bias[g] = tofl<T>(bih[j]) + tofl<T>(bhh[j]);
    if (LAYER == 0) {
      wx0[g] = tofl<T>(wih[j * 2]);
      wx1[g] = tofl<T>(wih[j * 2 + 1]);
    }
  }
  const int crow0 = (p0 * 2 + LAYER) * 256;
#pragma unroll
  for (int mi = 0; mi < 4; ++mi) {
#pragma unroll
    for (int r = 0; r < 4; ++r) {
      int b = ((nb & 1) << 7) + (wid >> 1) * 64 + mi * 16 + quad * 4 + r;
      float gv0 = acc[0][mi][r] + bias[0];
      float gv1 = acc[1][mi][r] + bias[1];
      float gv2 = acc[2][mi][r] + bias[2];
      float gv3 = acc[3][mi][r] + bias[3];
      if (LAYER == 0) {
        float x0 = tofl<T>(xin[(b * 64 + p0) * 2]);
        float x1 = tofl<T>(xin[(b * 64 + p0) * 2 + 1]);
        gv0 += x0 * wx0[0] + x1 * wx1[0];
        gv1 += x0 * wx0[1] + x1 * wx1[1];
        gv2 += x0 * wx0[2] + x1 * wx1[2];
        gv3 += x0 * wx0[3] + x1 * wx1[3];
      }
      float ig = sigf(gv0), fg = sigf(gv1);
      float gg = tanh_(gv2), og = sigf(gv3);
      size_t ro = ((size_t)(crow0 + b)) * 512 + hloc;
      float co   = tofl<T>(c0[ro]);
      float cnew = fg * co + ig * gg;
      float hnew = og * tanh_(cnew);
      out[HN_BASE + ro] = fromfl<T>(hnew);
      out[CN_BASE + ro] = fromfl<T>(cnew);
      if (LAYER == 1)
        out[(size_t)(b * 64 + p0) * 512 + hloc] = fromfl<T>(hnew);
    }
  }
}

template <int LAYER>
__global__ void __launch_bounds__(256)
lstm_layer(const void* xin, const void* h0, const void* c0,
           const void* wih, const void* whh, const void* bih, const void* bhh,
           const void* w_ih0_detect, void* out)
{
  __shared__ __align__(16) __hip_bfloat16 ldsA[128 * 64];
  __shared__ __align__(16) __hip_bfloat16 ldsW[128 * 64];
  if (detect_f32(w_ih0_detect)) {
    lstm_body<float, LAYER>((const float*)xin, (const float*)h0, (const float*)c0,
                            (const float*)wih, (const float*)whh,
                            (const float*)bih, (const float*)bhh,
                            (float*)out, ldsA, ldsW);
  } else {
    lstm_body<__hip_bfloat16, LAYER>((const __hip_bfloat16*)xin, (const __hip_bfloat16*)h0,
                                     (const __hip_bfloat16*)c0, (const __hip_bfloat16*)wih,
                                     (const __hip_bfloat16*)whh, (const __hip_bfloat16*)bih,
                                     (const __hip_bfloat16*)bhh, (__hip_bfloat16*)out,
                                     ldsA, ldsW);
  }
}

extern "C" void kernel_launch(void* const* d_in, const int* in_sizes, int n_in,
                              void* d_out, int out_size, void* d_ws, size_t ws_size,
                              hipStream_t stream) {
  dim3 block(256);
  if (d_ws != nullptr && ws_size >= WS_NEED) {
    // h0 slices -> A0 / A1B images (coalesced LDS-transpose)
    prep_panel_k<<<dim3(128, 2), block, 0, stream>>>(d_in[1], d_in[3], d_ws,
                                                     WS_A0, WS_A1B, 0);
    // W images (small)
    prep_W_k<<<dim3(48, 16), block, 0, stream>>>(d_in[4], d_in[7], d_in[8], d_in[3], d_ws);
    dim3 grid(2048);   // 1-D, XCD-chunk swizzled in-kernel
    lstm_dma<0><<<grid, block, 0, stream>>>(d_in[0], d_in[2], d_in[3],
                                            d_in[5], d_in[6], d_in[3], d_out, d_ws);
    // h_new0 (hn[:,0] slice of d_out) -> A1A image (coalesced)
    prep_panel_k<<<dim3(128, 1), block, 0, stream>>>(d_out, d_in[3], d_ws,
                                                     WS_A1A, WS_A1A, 1);
    lstm_dma<1><<<grid, block, 0, stream>>>(d_in[0], d_in[2], d_in[3],
                                            d_in[9], d_in[10], d_in[3], d_out, d_ws);
  } else {
    dim3 grid(MM / 128, HH / 32);
    lstm_layer<0><<<grid, block, 0, stream>>>(d_in[0], d_in[1], d_in[2],
                                              d_in[3], d_in[4], d_in[5], d_in[6],
                                              d_in[3], d_out);
    lstm_layer<1><<<grid, block, 0, stream>>>(d_in[0], d_in[1], d_in[2],
                                              d_in[7], d_in[8], d_in[9], d_in[10],
                                              d_in[3], d_out);
  }
}

// Round 10
// 451.580 us; speedup vs baseline: 1.0700x; 1.0700x over previous
//
#include <hip/hip_runtime.h>
#include <hip/hip_bf16.h>

// Problem constants
#define PP 64
#define BB 256
#define HH 512
#define MM (PP * BB)          // 16384 fused batch rows

// d_out layout: out (B,P,H) | hn (P,2,B,H) | cn (P,2,B,H)
#define HN_BASE (BB * PP * HH)                 // 8388608
#define CN_BASE (HN_BASE + PP * 2 * BB * HH)   // 25165824

// ---- workspace layout (bytes): FRAGMENT-ORDER bf16 tile images, BK=32 ----
// 8 KB tile = 512 slots of 16B, slot = rb*64 + lane (lane = qd*16 + lr):
//   A tiles [pb 0..127][kt32]: lane holds A[rb*16+lr][kt32*32 + qd*8 ..+8]
//   W tiles [hb 0..15][kt32]:  rb=g*2+half -> W row g*512+hb*32+half*16+lr
#define TILE8K 8192
#define WS_A0   0ull                          // h0[:,0]  image    16 MiB  (16 kt32)
#define WS_A1A  16777216ull                   // h_new0   image    16 MiB  (written by L0)
#define WS_A1B  33554432ull                   // h0[:,1]  image    16 MiB  (16 kt32)
#define WS_W0   50331648ull                   // whh0  image   2 MiB (16 hb x 16 kt32)
#define WS_W1A  52428800ull                   // wih1  image   2 MiB
#define WS_W1B  54525952ull                   // whh1  image   2 MiB
#define WS_NEED 56623104ull

typedef __attribute__((ext_vector_type(8))) short bf16x8;
typedef __attribute__((ext_vector_type(4))) float floatx4;

__device__ __forceinline__ float sigf(float x) { return 1.0f / (1.0f + __expf(-x)); }
__device__ __forceinline__ float tanh_(float x) { return 2.0f / (1.0f + __expf(-2.0f * x)) - 1.0f; }

// float -> bf16 bits, round-nearest-even (finite inputs only)
__device__ __forceinline__ short f2bf(float f) {
  unsigned u = __float_as_uint(f);
  u = (u + 0x7FFFu + ((u >> 16) & 1u)) >> 16;
  return (short)u;
}

template <typename T>
__device__ __forceinline__ float tofl(T v);
template <> __device__ __forceinline__ float tofl<float>(float v) { return v; }
template <> __device__ __forceinline__ float tofl<__hip_bfloat16>(__hip_bfloat16 v) { return __bfloat162float(v); }

template <typename T>
__device__ __forceinline__ T fromfl(float v);
template <> __device__ __forceinline__ float fromfl<float>(float v) { return v; }
template <> __device__ __forceinline__ __hip_bfloat16 fromfl<__hip_bfloat16>(float v) { return __float2bfloat16(v); }

// load 8 consecutive elements as bf16x8 (16B-aligned for bf16, 32B for f32)
template <typename T>
__device__ __forceinline__ bf16x8 load8(const T* p);
template <> __device__ __forceinline__ bf16x8 load8<__hip_bfloat16>(const __hip_bfloat16* p) {
  return *(const bf16x8*)p;
}
template <> __device__ __forceinline__ bf16x8 load8<float>(const float* p) {
  float4 f0 = *(const float4*)p;
  float4 f1 = *((const float4*)p + 1);
  bf16x8 v;
  v[0] = f2bf(f0.x); v[1] = f2bf(f0.y); v[2] = f2bf(f0.z); v[3] = f2bf(f0.w);
  v[4] = f2bf(f1.x); v[5] = f2bf(f1.y); v[6] = f2bf(f1.z); v[7] = f2bf(f1.w);
  return v;
}

// fp32 vs bf16 buffer detection (see original kernel comment)
__device__ __forceinline__ bool detect_f32(const void* w_ih0) {
  const unsigned short* p = (const unsigned short*)w_ih0;
  int l = threadIdx.x & 63;
  unsigned short a = p[2 * l], b = p[2 * l + 1];
  int big = ((a & 0x7F80) >= 0x3F80) || ((b & 0x7F80) >= 0x3F80);
  return __any(big);
}

// async global -> LDS, 16 bytes per lane. LDS dest is wave-uniform + lane*16.
__device__ __forceinline__ void gload16(void* ldsp, const void* g) {
  __builtin_amdgcn_global_load_lds(
      (const __attribute__((address_space(1))) unsigned int*)g,
      (__attribute__((address_space(3))) unsigned int*)ldsp, 16, 0, 0);
}

// ============================================================================
// prep_panel: coalesced LDS-transpose of one 64-col chunk of a [128 x 512]
// panel into 2 fragment tiles (8 KB each).  Reads 256B row-segments
// (coalesced), transposes through 16 KB LDS, dumps linearly (16B/lane).
// grid (128 pb, 8 cc, 2 l), block 256.
// ============================================================================
template <typename T>
__device__ __forceinline__ void prep_panel_body(const T* __restrict__ src, char* __restrict__ dst,
                                                char* lds, int cc) {
  const int tid = threadIdx.x;
#pragma unroll
  for (int i = 0; i < 8; ++i) {
    int idx = i * 256 + tid;
    int row = idx >> 4;                    // 0..127 (16 lanes per row-segment)
    int c   = (idx & 15) * 4;              // col within the 64-col chunk
    const T* p = src + (size_t)row * 512 + cc * 64 + c;
    short4 s;
    if constexpr (sizeof(T) == 4) {
      float4 f = *(const float4*)p;
      s.x = f2bf(f.x); s.y = f2bf(f.y); s.z = f2bf(f.z); s.w = f2bf(f.w);
    } else {
      s = *(const short4*)p;
    }
    int tile = c >> 5;                     // 0/1
    int qd   = (c & 31) >> 3;
    int e0   = c & 7;                      // 0 or 4
    int rb   = row >> 4, lr = row & 15;
    *(short4*)(lds + tile * 8192 + ((rb * 64 + qd * 16 + lr) * 16) + e0 * 2) = s;
  }
  __syncthreads();
#pragma unroll
  for (int i = 0; i < 4; ++i) {
    int idx = i * 256 + tid;               // 0..1023 -> tiles cc*2 and cc*2+1
    int kt  = cc * 2 + (idx >> 9);
    *(bf16x8*)(dst + (size_t)kt * TILE8K + (size_t)(idx & 511) * 16) =
        *(const bf16x8*)(lds + (size_t)idx * 16);
  }
}

__global__ void __launch_bounds__(256)
prep_panel_k(const void* tensor, const void* det, void* ws,
             unsigned long long off0, unsigned long long off1) {
  const int pb = blockIdx.x, cc = blockIdx.y, l = blockIdx.z;
  __shared__ __align__(16) char lds[16384];
  char* dst = (char*)ws + (l ? off1 : off0) + (size_t)pb * 16 * TILE8K;
  const size_t srcoff = (((size_t)(pb >> 1) * 2 + l) * 256 + (size_t)(pb & 1) * 128) * 512;
  if (detect_f32(det)) {
    prep_panel_body<float>((const float*)tensor + srcoff, dst, lds, cc);
  } else {
    prep_panel_body<__hip_bfloat16>((const __hip_bfloat16*)tensor + srcoff, dst, lds, cc);
  }
}

// ============================================================================
// W tiles from the three [2048,512] matrices. grid (48 = 3*16, 16 kt32), block 256.
// ============================================================================
template <typename T>
__device__ __forceinline__ void prep_W_body(const T* __restrict__ w0, const T* __restrict__ w1a,
                                            const T* __restrict__ w1b, char* __restrict__ ws) {
  const int m = blockIdx.x >> 4, hb = blockIdx.x & 15, kt = blockIdx.y;
  const T* src = (m == 0) ? w0 : (m == 1 ? w1a : w1b);
  const size_t base = (m == 0) ? WS_W0 : (m == 1 ? WS_W1A : WS_W1B);
  char* dst = ws + base + ((size_t)(hb * 16 + kt)) * TILE8K;
  const int tid = threadIdx.x;
#pragma unroll
  for (int i = 0; i < 2; ++i) {
    int idx = i * 256 + tid;
    int ln  = idx & 63;
    int rb  = idx >> 6;               // rb = g*2 + half
    int g   = rb >> 1, half = rb & 1;
    int j   = g * 512 + hb * 32 + half * 16 + (ln & 15);   // row in [2048,512]
    int col = kt * 32 + (ln >> 4) * 8;
    *(bf16x8*)(dst + (size_t)idx * 16) = load8<T>(src + (size_t)j * 512 + col);
  }
}

__global__ void __launch_bounds__(256) prep_W_k(const void* w0, const void* w1a, const void* w1b,
                                                const void* det, void* ws) {
  if (detect_f32(det)) prep_W_body<float>((const float*)w0, (const float*)w1a, (const float*)w1b, (char*)ws);
  else prep_W_body<__hip_bfloat16>((const __hip_bfloat16*)w0, (const __hip_bfloat16*)w1a,
                                   (const __hip_bfloat16*)w1b, (char*)ws);
}

// ============================================================================
// Main layer kernel (R8 config — best measured): BK=32 DMA double-buffer,
// plain __syncthreads per iteration, grid (16 hb, 128 nb) UNSWIZZLED.
// L0 additionally emits its complete A1A fragment tile [nb][hb] via an LDS
// transpose + one coalesced 8 KB dump (replaces the prep_mid dispatch).
// ============================================================================
template <typename T, int LAYER>
__device__ __forceinline__ void lstm_dma_body(
    const T* __restrict__ xin, const T* __restrict__ c0,
    const T* __restrict__ wih, const T* __restrict__ bih, const T* __restrict__ bhh,
    T* __restrict__ out, char* __restrict__ ws, char* lds)
{
  const int tid  = threadIdx.x;
  const int hb   = blockIdx.x;   // h-block 0..15
  const int nb   = blockIdx.y;   // n-block 0..127 (== pb of A tiles)
  const int lane = tid & 63;
  const int wid  = tid >> 6;
  const int quad = lane >> 4;
  const int lrow = lane & 15;
  const int p0   = nb >> 1;

  floatx4 acc[4][4];             // [gate][mi]
#pragma unroll
  for (int g = 0; g < 4; ++g)
#pragma unroll
    for (int mi = 0; mi < 4; ++mi)
#pragma unroll
      for (int q = 0; q < 4; ++q) acc[g][mi][q] = 0.0f;

  const int a_rb0  = (wid >> 1) * 4;   // first A row-block for this wave
  const int w_half = wid & 1;

  constexpr int KITERS = (LAYER == 0) ? 16 : 32;   // K = 512 or 1024, BK=32

  auto stage = [&](int buf, int kt) {
    const char *at, *wt;
    if (LAYER == 0) {
      at = ws + WS_A0  + ((size_t)(nb * 16 + kt)) * TILE8K;
      wt = ws + WS_W0  + ((size_t)(hb * 16 + kt)) * TILE8K;
    } else if (kt < 16) {
      at = ws + WS_A1A + ((size_t)(nb * 16 + kt)) * TILE8K;
      wt = ws + WS_W1A + ((size_t)(hb * 16 + kt)) * TILE8K;
    } else {
      at = ws + WS_A1B + ((size_t)(nb * 16 + kt - 16)) * TILE8K;
      wt = ws + WS_W1B + ((size_t)(hb * 16 + kt - 16)) * TILE8K;
    }
    char* la = lds + buf * 16384;
    char* lw = la + TILE8K;
#pragma unroll
    for (int i = 0; i < 2; ++i) {
      int base = (i * 4 + wid) * 1024;       // wave-uniform LDS dest (verbatim copy)
      int off  = base + lane * 16;           // per-lane global source
      gload16(la + base, at + off);
      gload16(lw + base, wt + off);
    }
  };

  // prologue: fill buffer 0 (syncthreads' implicit vmcnt(0) drains the DMA)
  stage(0, 0);
  __syncthreads();

#pragma unroll
  for (int kt = 0; kt < KITERS; ++kt) {
    const int cur = kt & 1;
    if (kt + 1 < KITERS) stage(cur ^ 1, kt + 1);   // DMA in flight during MFMAs

    const char* la = lds + cur * 16384;
    const char* lw = la + TILE8K;
    bf16x8 aF[4], wF[4];
#pragma unroll
    for (int mi = 0; mi < 4; ++mi)
      aF[mi] = *(const bf16x8*)(la + ((a_rb0 + mi) * 1024) + lane * 16);
#pragma unroll
    for (int g = 0; g < 4; ++g)
      wF[g] = *(const bf16x8*)(lw + ((g * 2 + w_half) * 1024) + lane * 16);
#pragma unroll
    for (int g = 0; g < 4; ++g)
#pragma unroll
      for (int mi = 0; mi < 4; ++mi)
        acc[g][mi] = __builtin_amdgcn_mfma_f32_16x16x32_bf16(
            aF[mi], wF[g], acc[g][mi], 0, 0, 0);

    // barrier: (a) all waves done reading buf cur; (b) implicit vmcnt(0)
    // drain -> buf cur^1 DMA complete.
    __syncthreads();
  }

  // --- epilogue: biases + K=2 input GEMM (L0) + LSTM cell + stores ---
  const int hloc = hb * 32 + w_half * 16 + lrow;   // global h (C/D col = lane&15)
  float bias[4], wx0[4], wx1[4];
#pragma unroll
  for (int g = 0; g < 4; ++g) {
    int j = g * 512 + hloc;
    bias[g] = tofl<T>(bih[j]) + tofl<T>(bhh[j]);
    if (LAYER == 0) {
      wx0[g] = tofl<T>(wih[j * 2]);
      wx1[g] = tofl<T>(wih[j * 2 + 1]);
    }
  }
  const int crow0 = (p0 * 2 + LAYER) * 256;
  const int qd_h = (hloc >> 3) & 3;    // quad within this block's 32-col tile
  const int el_h = hloc & 7;           // element within the 8-wide chunk

#pragma unroll
  for (int mi = 0; mi < 4; ++mi) {
#pragma unroll
    for (int r = 0; r < 4; ++r) {
      // C/D layout: row(m=batch) = quad*4 + r, col(n=h) = lane&15
      int rr = (wid >> 1) * 64 + mi * 16 + quad * 4 + r;   // row within 128-row tile
      int b  = ((nb & 1) << 7) + rr;
      float gv0 = acc[0][mi][r] + bias[0];
      float gv1 = acc[1][mi][r] + bias[1];
      float gv2 = acc[2][mi][r] + bias[2];
      float gv3 = acc[3][mi][r] + bias[3];
      if (LAYER == 0) {
        float x0 = tofl<T>(xin[(b * 64 + p0) * 2]);
        float x1 = tofl<T>(xin[(b * 64 + p0) * 2 + 1]);
        gv0 += x0 * wx0[0] + x1 * wx1[0];
        gv1 += x0 * wx0[1] + x1 * wx1[1];
        gv2 += x0 * wx0[2] + x1 * wx1[2];
        gv3 += x0 * wx0[3] + x1 * wx1[3];
      }
      float ig = sigf(gv0), fg = sigf(gv1);
      float gg = tanh_(gv2), og = sigf(gv3);
      size_t ro = ((size_t)(crow0 + b)) * 512 + hloc;
      float co   = tofl<T>(c0[ro]);
      float cnew = fg * co + ig * gg;
      float hnew = og * tanh_(cnew);
      out[HN_BASE + ro] = fromfl<T>(hnew);
      out[CN_BASE + ro] = fromfl<T>(cnew);
      if (LAYER == 0) {
        // this block's 128x32 hnew = exactly A1A tile [nb][hb]; stage in LDS
        // fragment layout: slot = (rr>>4)*64 + qd_h*16 + (rr&15), elem el_h
        int slot = ((rr >> 4) * 64) + qd_h * 16 + (rr & 15);
        *(short*)(lds + slot * 16 + el_h * 2) = f2bf(hnew);
      }
      if (LAYER == 1)
        out[(size_t)(b * 64 + p0) * 512 + hloc] = fromfl<T>(hnew);
    }
  }

  if (LAYER == 0) {
    __syncthreads();   // all lanes' LDS fragment writes complete
    char* a1a_tile = ws + WS_A1A + ((size_t)(nb * 16 + hb)) * TILE8K;
#pragma unroll
    for (int i = 0; i < 2; ++i) {
      int idx = i * 256 + tid;
      *(bf16x8*)(a1a_tile + (size_t)idx * 16) = *(const bf16x8*)(lds + (size_t)idx * 16);
    }
  }
}

template <int LAYER>
__global__ void __launch_bounds__(256, 4)
lstm_dma(const void* xin, const void* c0, const void* wih,
         const void* bih, const void* bhh, const void* det,
         void* out, void* ws)
{
  __shared__ __align__(16) char lds[2 * 16384];   // dbuf x (A 8K + W 8K) = 32 KB
  if (detect_f32(det)) {
    lstm_dma_body<float, LAYER>((const float*)xin, (const float*)c0, (const float*)wih,
                                (const float*)bih, (const float*)bhh,
                                (float*)out, (char*)ws, lds);
  } else {
    lstm_dma_body<__hip_bfloat16, LAYER>((const __hip_bfloat16*)xin, (const __hip_bfloat16*)c0,
                                         (const __hip_bfloat16*)wih, (const __hip_bfloat16*)bih,
                                         (const __hip_bfloat16*)bhh,
                                         (__hip_bfloat16*)out, (char*)ws, lds);
  }
}

// ============================================================================
// Fallback (original verified kernel) — used if workspace is too small/absent.
// ============================================================================
template <typename T, int LAYER>
__device__ __forceinline__ void lstm_body(
    const T* __restrict__ xin, const T* __restrict__ h0, const T* __restrict__ c0,
    const T* __restrict__ wih, const T* __restrict__ whh,
    const T* __restrict__ bih, const T* __restrict__ bhh,
    T* out, __hip_bfloat16* ldsA, __hip_bfloat16* ldsW)
{
  const int tid  = threadIdx.x;
  const int nb   = blockIdx.x;
  const int hb   = blockIdx.y;
  const int lane = tid & 63;
  const int wid  = tid >> 6;
  const int quad = lane >> 4;
  const int lrow = lane & 15;
  const int p0   = nb >> 1;

  floatx4 acc[4][4];
#pragma unroll
  for (int g = 0; g < 4; ++g)
#pragma unroll
    for (int mi = 0; mi < 4; ++mi)
#pragma unroll
      for (int q = 0; q < 4; ++q) acc[g][mi][q] = 0.0f;

  int arow[4], wrow[4];
#pragma unroll
  for (int mi = 0; mi < 4; ++mi) arow[mi] = (wid >> 1) * 64 + mi * 16 + lrow;
#pragma unroll
  for (int g = 0; g < 4; ++g) wrow[g] = g * 32 + (wid & 1) * 16 + lrow;

  const int sr = tid >> 3;
  const int sc = tid & 7;
  const int KITERS = (LAYER == 0) ? 8 : 16;

  for (int kt = 0; kt < KITERS; ++kt) {
    bf16x8 ra[4], rw[4];
#pragma unroll
    for (int round = 0; round < 4; ++round) {
      int r = sr + round * 32;
      int b = ((nb & 1) << 7) + r;
      const T* srcA;
      if (LAYER == 0) {
        srcA = h0 + ((size_t)((p0 * 2) * 256 + b)) * 512 + kt * 64 + sc * 8;
      } else {
        if (kt < 8)
          srcA = out + HN_BASE + ((size_t)((p0 * 2) * 256 + b)) * 512 + kt * 64 + sc * 8;
        else
          srcA = h0 + ((size_t)((p0 * 2 + 1) * 256 + b)) * 512 + (kt - 8) * 64 + sc * 8;
      }
      ra[round] = load8<T>(srcA);

      int j = (r >> 5) * 512 + hb * 32 + (r & 31);
      const T* srcW;
      if (LAYER == 0) {
        srcW = whh + (size_t)j * 512 + kt * 64 + sc * 8;
      } else {
        if (kt < 8) srcW = wih + (size_t)j * 512 + kt * 64 + sc * 8;
        else        srcW = whh + (size_t)j * 512 + (kt - 8) * 64 + sc * 8;
      }
      rw[round] = load8<T>(srcW);
    }

    __syncthreads();
#pragma unroll
    for (int round = 0; round < 4; ++round) {
      int r = sr + round * 32;
      int p = sc ^ (r & 7);
      *(bf16x8*)((char*)ldsA + r * 128 + p * 16) = ra[round];
      *(bf16x8*)((char*)ldsW + r * 128 + p * 16) = rw[round];
    }
    __syncthreads();

#pragma unroll
    for (int ks = 0; ks < 2; ++ks) {
      bf16x8 aF[4], wF[4];
#pragma unroll
      for (int mi = 0; mi < 4; ++mi) {
        int ch = (ks * 4 + quad) ^ (arow[mi] & 7);
        aF[mi] = *(const bf16x8*)((const char*)ldsA + arow[mi] * 128 + ch * 16);
      }
#pragma unroll
      for (int g = 0; g < 4; ++g) {
        int ch = (ks * 4 + quad) ^ (wrow[g] & 7);
        wF[g] = *(const bf16x8*)((const char*)ldsW + wrow[g] * 128 + ch * 16);
      }
#pragma unroll
      for (int g = 0; g < 4; ++g)
#pragma unroll
        for (int mi = 0; mi < 4; ++mi)
          acc[g][mi] = __builtin_amdgcn_mfma_f32_16x16x32_bf16(
              aF[mi], wF[g], acc[g][mi], 0, 0, 0);
    }
  }

  const int hloc = hb * 32 + (wid & 1) * 16 + lrow;
  float bias[4], wx0[4], wx1[4];
#pragma unroll
  for (int g = 0; g < 4; ++g) {
    int j = g * 512 + hloc;
    bias[g] = tofl<T>(bih[j]) + tofl<T>(bhh[j]);
    if (LAYER == 0) {
      wx0[g] = tofl<T>(wih[j * 2]);
      wx1[g] = tofl<T>(wih[j * 2 + 1]);
    }
  }
  const int crow0 = (p0 * 2 + LAYER) * 256;
#pragma unroll
  for (int mi = 0; mi < 4; ++mi) {
#pragma unroll
    for (int r = 0; r < 4; ++r) {
      int b = ((nb & 1) << 7) + (wid >> 1) * 64 + mi * 16 + quad * 4 + r;
      float gv0 = acc[0][mi][r] + bias[0];
      float gv1 = acc[1][mi][r] + bias[1];
      float gv2 = acc[2][mi][r] + bias[2];
      float gv3 = acc[3][mi][r] + bias[3];
      if (LAYER == 0) {
        float x0 = tofl<T>(xin[(b * 64 + p0) * 2]);
        float x1 = tofl<T>(xin[(b * 64 + p0) * 2 + 1]);
        gv0 += x0 * wx0[0] + x1 * wx1[0];
        gv1 += x0 * wx0[1] + x1 * wx1[1];
        gv2 += x0 * wx0[2] + x1 * wx1[2];
        gv3 += x0 * wx0[3] + x1 * wx1[3];
      }
      float ig = sigf(gv0), fg = sigf(gv1);
      float gg = tanh_(gv2), og = sigf(gv3);
      size_t ro = ((size_t)(crow0 + b)) * 512 + hloc;
      float co   = tofl<T>(c0[ro]);
      float cnew = fg * co + ig * gg;
      float hnew = og * tanh_(cnew);
      out[HN_BASE + ro] = fromfl<T>(hnew);
      out[CN_BASE + ro] = fromfl<T>(cnew);
      if (LAYER == 1)
        out[(size_t)(b * 64 + p0) * 512 + hloc] = fromfl<T>(hnew);
    }
  }
}

template <int LAYER>
__global__ void __launch_bounds__(256)
lstm_layer(const void* xin, const void* h0, const void* c0,
           const void* wih, const void* whh, const void* bih, const void* bhh,
           const void* w_ih0_detect, void* out)
{
  __shared__ __align__(16) __hip_bfloat16 ldsA[128 * 64];
  __shared__ __align__(16) __hip_bfloat16 ldsW[128 * 64];
  if (detect_f32(w_ih0_detect)) {
    lstm_body<float, LAYER>((const float*)xin, (const float*)h0, (const float*)c0,
                            (const float*)wih, (const float*)whh,
                            (const float*)bih, (const float*)bhh,
                            (float*)out, ldsA, ldsW);
  } else {
    lstm_body<__hip_bfloat16, LAYER>((const __hip_bfloat16*)xin, (const __hip_bfloat16*)h0,
                                     (const __hip_bfloat16*)c0, (const __hip_bfloat16*)wih,
                                     (const __hip_bfloat16*)whh, (const __hip_bfloat16*)bih,
                                     (const __hip_bfloat16*)bhh, (__hip_bfloat16*)out,
                                     ldsA, ldsW);
  }
}

extern "C" void kernel_launch(void* const* d_in, const int* in_sizes, int n_in,
                              void* d_out, int out_size, void* d_ws, size_t ws_size,
                              hipStream_t stream) {
  dim3 block(256);
  if (d_ws != nullptr && ws_size >= WS_NEED) {
    // h0 slices -> A0 / A1B images (coalesced LDS-transpose, 2048 blocks)
    prep_panel_k<<<dim3(128, 8, 2), block, 0, stream>>>(d_in[1], d_in[3], d_ws,
                                                        WS_A0, WS_A1B);
    // W images (small)
    prep_W_k<<<dim3(48, 16), block, 0, stream>>>(d_in[4], d_in[7], d_in[8], d_in[3], d_ws);
    dim3 grid(HH / 32, MM / 128);   // (16 hb, 128 nb) — R8 config, unswizzled
    lstm_dma<0><<<grid, block, 0, stream>>>(d_in[0], d_in[2], d_in[3],
                                            d_in[5], d_in[6], d_in[3], d_out, d_ws);
    // (A1A image written directly by lstm_dma<0> epilogue — no prep_mid)
    lstm_dma<1><<<grid, block, 0, stream>>>(d_in[0], d_in[2], d_in[3],
                                            d_in[9], d_in[10], d_in[3], d_out, d_ws);
  } else {
    dim3 grid(MM / 128, HH / 32);
    lstm_layer<0><<<grid, block, 0, stream>>>(d_in[0], d_in[1], d_in[2],
                                              d_in[3], d_in[4], d_in[5], d_in[6],
                                              d_in[3], d_out);
    lstm_layer<1><<<grid, block, 0, stream>>>(d_in[0], d_in[1], d_in[2],
                                              d_in[7], d_in[8], d_in[9], d_in[10],
                                              d_in[3], d_out);
  }
}